// Round 12
// baseline (635.217 us; speedup 1.0000x reference)
//
#include <hip/hip_runtime.h>
#include <hip/hip_bf16.h>

// LSTM B=256 T=512 H=256 E=6 V=10 C=10. fp32 in/out.
// ROUND 12: 128 blocks x 512 threads, 2 batch cols/block, 8x n-slot dup ->
// 1 h-element/thread (r11 structure). This round: LDS bank-conflict fixes
// (tbl transposed [d][row][4g]; hbuf stride 320B so col0/col1 bank-disjoint;
// packed h-store via shfl_xor + single b32 from si==0 lanes) and rcp-merged
// activations (8 transc/elem, was 10; med3 clamp vs overflow).
// INT8 MFMA (mfma_i32_16x16x64_i8) with register-resident per-row-quantized
// weights; h @127 double-buffered LDS, 1 barrier/step. acc select = constant-
// index cndmask tree (r9 lesson: NEVER divergent-index a register array).

typedef __attribute__((ext_vector_type(4))) int   int4v;
typedef __attribute__((ext_vector_type(4))) float float4v;

#define MFMA_I8(a, b, c) __builtin_amdgcn_mfma_i32_16x16x64_i8(a, b, c, 0, 0, 0)

#define K_TANH (-2.8853900817779268f)   // exp2(K_TANH*x) = e^(-2x)
#define K_SIG  (-1.4426950408889634f)   // exp2(K_SIG*x)  = e^(-x)

#define HSTRIDE 320                     // bytes per col in hbuf: 80 dw == 16 mod 32

__device__ __forceinline__ short f2b(float f) {
    __hip_bfloat16 b = __float2bfloat16(f); return *(short*)&b;
}
__device__ __forceinline__ float b2f(short s) {
    union { unsigned int u; float f; } v; v.u = ((unsigned int)(unsigned short)s) << 16; return v.f;
}
__device__ __forceinline__ float fexp2(float x) {
#if __has_builtin(__builtin_amdgcn_exp2f)
    return __builtin_amdgcn_exp2f(x);
#else
    return __expf(x * 0.6931471805599453f);
#endif
}
__device__ __forceinline__ float frcp(float x) { return __builtin_amdgcn_rcpf(x); }
__device__ __forceinline__ float clamp60(float x) { return __builtin_amdgcn_fmed3f(x, -60.f, 60.f); }

__global__ __attribute__((amdgpu_flat_work_group_size(512, 512), amdgpu_waves_per_eu(2, 2)))
void lstm_i8(
    const int* __restrict__ x,
    const float* __restrict__ emb,
    const float* __restrict__ Wxg, const float* __restrict__ Whg, const float* __restrict__ bg,
    const float* __restrict__ Wxi, const float* __restrict__ Whi, const float* __restrict__ bi,
    const float* __restrict__ Wxf, const float* __restrict__ Whf, const float* __restrict__ bff,
    const float* __restrict__ Wxo, const float* __restrict__ Who, const float* __restrict__ bo,
    const float* __restrict__ Wp, const float* __restrict__ bp,
    float* __restrict__ out)
{
    const int tid = threadIdx.x, bid = blockIdx.x;
    const int c0 = bid * 2;                 // 2 batch columns per block
    const int w = tid >> 6, lane = tid & 63;
    const int l = lane & 15, q = lane >> 4;
    const int col = l & 1;                  // this thread's column (8x dup)
    const int g3  = (l >> 1) & 7;           // selects (rr, i)
    const int si  = g3 & 3;                 // acc reg index
    const int srr = g3 >> 2;                // row tile
    const int rw  = 32 * w;
    const int row = rw + 16 * srr + 4 * q + si;   // this thread's hidden row

    __shared__ __align__(16) unsigned int hbuf[2][2 * HSTRIDE / 4];  // h i8 [parity][col][k]
    __shared__ __align__(16) short hfin[2 * 264];                    // final h bf16 [col][k]
    __shared__ unsigned char xdig2[512 * 2];                         // [t][col]
    __shared__ __align__(16) float tblT[10 * 1024];                  // [d][row][4 gates] f32
    __shared__ float scaleL[4 * 256];                                // per-gate per-row max|W|

    const float* WxT[4] = {Wxg, Wxi, Wxf, Wxo};
    const float* WhT[4] = {Whg, Whi, Whf, Who};

    // ---- init: zero h buf0, stage digits ----
    if (tid < 2 * HSTRIDE / 4) hbuf[0][tid] = 0u;
    for (int i = tid; i < 1024; i += 512)
        xdig2[i] = (unsigned char)x[(c0 + (i & 1)) * 512 + (i >> 1)];

    // ---- x-path table, transposed + gate-scale folded: tblT[d][r][g] ----
    for (int i = tid; i < 2560; i += 512) {
        int d = i >> 8, r = i & 255;          // consecutive lanes -> consecutive r
        float4v v;
        #pragma unroll
        for (int g = 0; g < 4; g++) {
            float s = 0.f;
            #pragma unroll
            for (int e = 0; e < 6; e++) s += WxT[g][r * 6 + e] * emb[d * 6 + e];
            v[g] = s * (g == 0 ? K_TANH : K_SIG);
        }
        *(float4v*)&tblT[d * 1024 + r * 4] = v;
    }

    // ---- weight quantization: per-row scale, i8 A-frags in registers ----
    // A[m=lane&15 -> row rw+16rr+l][k = 64kt+16q+j], both rr tiles per wave
    int4v wa[4][2][4];
    #pragma unroll
    for (int g = 0; g < 4; g++)
        #pragma unroll
        for (int rr = 0; rr < 2; rr++) {
            const float* Wr = WhT[g] + (rw + 16 * rr + l) * 256 + q * 16;
            float mx = 0.f;
            #pragma unroll
            for (int kt = 0; kt < 4; kt++)
                #pragma unroll
                for (int c4 = 0; c4 < 4; c4++) {
                    float4v v = *(const float4v*)(Wr + kt * 64 + c4 * 4);
                    #pragma unroll
                    for (int j = 0; j < 4; j++) mx = fmaxf(mx, fabsf(v[j]));
                }
            mx = fmaxf(mx, __shfl_xor(mx, 16));
            mx = fmaxf(mx, __shfl_xor(mx, 32));
            mx = fmaxf(mx, 1e-20f);
            if (q == 0) scaleL[g * 256 + rw + 16 * rr + l] = mx;
            float qs = 127.f / mx;
            #pragma unroll
            for (int kt = 0; kt < 4; kt++) {
                int4v f;
                #pragma unroll
                for (int dw = 0; dw < 4; dw++) {
                    float4v v = *(const float4v*)(Wr + kt * 64 + dw * 4);
                    int word = 0;
                    #pragma unroll
                    for (int byt = 0; byt < 4; byt++) {
                        int z = (int)rintf(v[byt] * qs);
                        word |= (z & 255) << (8 * byt);
                    }
                    f[dw] = word;
                }
                wa[g][rr][kt] = f;
            }
        }

    __syncthreads();   // scaleL/tblT/xdig2/hbuf[0] visible

    // ---- loop-invariant: dequant scales (this thread's row), biases (this col) ----
    float dscl[4];
    #pragma unroll
    for (int g = 0; g < 4; g++) {
        float kk = (g == 0 ? K_TANH : K_SIG) * (1.f / 16129.f);   // 127^2
        dscl[g] = scaleL[g * 256 + row] * kk;
    }
    float bSc[4];
    bSc[0] = bg[c0 + col] * K_TANH; bSc[1] = bi[c0 + col] * K_SIG;
    bSc[2] = bff[c0 + col] * K_SIG; bSc[3] = bo[c0 + col] * K_SIG;

    const bool bi1 = (si & 1) != 0;
    const bool bi2 = (si & 2) != 0;
    const bool brr = (srr != 0);
    const float* tprow = tblT + row * 4;     // + d*1024 at runtime
    const int hoff = col * HSTRIDE + rw + 16 * srr + 4 * q;   // this thread's h dword

    float cs = 0.f, hl = 0.f;

    for (int t = 0; t < 512; t++) {
        const int p = t & 1;
        const char* hbase = (const char*)hbuf[p] + col * HSTRIDE + q * 16;   // dup lanes broadcast

        int4v acc[4][2];
        #pragma unroll
        for (int g = 0; g < 4; g++)
            #pragma unroll
            for (int rr = 0; rr < 2; rr++)
                acc[g][rr] = (int4v){0, 0, 0, 0};

        int dg = xdig2[t * 2 + col];
        float4v tb = *(const float4v*)(tprow + dg * 1024);   // {tg,ti,tf,to} kg-scaled

        #pragma unroll
        for (int kt = 0; kt < 4; kt++) {
            int4v hf = *(const int4v*)(hbase + kt * 64);   // B[k=64kt+16q+j][n: col l&1, dup]
            #pragma unroll
            for (int g = 0; g < 4; g++) {
                acc[g][0] = MFMA_I8(wa[g][0][kt], hf, acc[g][0]);
                acc[g][1] = MFMA_I8(wa[g][1][kt], hf, acc[g][1]);
            }
        }
        // no barrier: writes go to the other h buffer

        // ---- elementwise: ONE element (row, col) per thread ----
        // select acc[g][srr][si] via constant-index cndmask tree (7 per gate)
        int av[4];
        #pragma unroll
        for (int g = 0; g < 4; g++) {
            int s00 = bi1 ? acc[g][0][1] : acc[g][0][0];
            int s01 = bi1 ? acc[g][0][3] : acc[g][0][2];
            int s10 = bi1 ? acc[g][1][1] : acc[g][1][0];
            int s11 = bi1 ? acc[g][1][3] : acc[g][1][2];
            int s0  = bi2 ? s01 : s00;
            int s1  = bi2 ? s11 : s10;
            av[g]   = brr ? s1 : s0;
        }
        {
            float pg = clamp60(fmaf((float)av[0], dscl[0], tb[0] + bSc[0]));
            float pi = clamp60(fmaf((float)av[1], dscl[1], tb[1] + bSc[1]));
            float pf = clamp60(fmaf((float)av[2], dscl[2], tb[2] + bSc[2]));
            float po = clamp60(fmaf((float)av[3], dscl[3], tb[3] + bSc[3]));
            float Eg = fexp2(pg), Ei = fexp2(pi), Ef = fexp2(pf), Eo = fexp2(po);
            // tanh(g)*sig(i) = (1-Eg) / ((1+Eg)(1+Ei));  c += cs*sig(f)
            float t1 = (1.f - Eg) * frcp((1.f + Eg) * (1.f + Ei));
            float c  = fmaf(cs, frcp(1.f + Ef), t1);
            cs = c;
            float Ec = fexp2(clamp60(K_TANH * c));
            float hh = (1.f - Ec) * frcp((1.f + Ec) * (1.f + Eo));   // tanh(c)*sig(o)
            hl = hh;
            int hq = (int)rintf(hh * 127.f) & 255;
            // pack 4 row-bytes (si=0..3 live in lanes l, l+2, l+4, l+6) -> one b32
            int w1 = hq | (__shfl_xor(hq, 2) << 8);
            int w2 = w1 | (__shfl_xor(w1, 4) << 16);
            if (si == 0)
                *(int*)((char*)hbuf[1 - p] + hoff) = w2;
        }
        __syncthreads();   // h_t (other buffer) fully written; h_{t-1} reads all done
    }

    // ---- stage final h (exact f32->bf16) for projection ----
    hfin[col * 264 + row] = f2b(hl);
    __syncthreads();

    // ---- projection: out[c0+col][cls] = Wp[cls] . h_final + bp[cls] ----
    if (tid < 20) {
        int pc = tid / 10, cls = tid - pc * 10;
        const short* hcol = &hfin[pc * 264];
        const float* wrow = Wp + cls * 256;
        float s = 0.f;
        #pragma unroll 8
        for (int k = 0; k < 256; k++) s += b2f(hcol[k]) * wrow[k];
        out[(c0 + pc) * 10 + cls] = s + bp[cls];
    }
}

extern "C" void kernel_launch(void* const* d_in, const int* in_sizes, int n_in,
                              void* d_out, int out_size, void* d_ws, size_t ws_size,
                              hipStream_t stream) {
    const int*   x   = (const int*)d_in[0];
    const float* emb = (const float*)d_in[1];
    const float* Wxg = (const float*)d_in[2];
    const float* Whg = (const float*)d_in[3];
    const float* bg  = (const float*)d_in[4];
    const float* Wxi = (const float*)d_in[5];
    const float* Whi = (const float*)d_in[6];
    const float* bi  = (const float*)d_in[7];
    const float* Wxf = (const float*)d_in[8];
    const float* Whf = (const float*)d_in[9];
    const float* bff = (const float*)d_in[10];
    const float* Wxo = (const float*)d_in[11];
    const float* Who = (const float*)d_in[12];
    const float* bo  = (const float*)d_in[13];
    const float* Wp  = (const float*)d_in[14];
    const float* bp  = (const float*)d_in[15];

    hipLaunchKernelGGL(lstm_i8, dim3(128), dim3(512), 0, stream,
                       x, emb, Wxg, Whg, bg, Wxi, Whi, bi, Wxf, Whf, bff,
                       Wxo, Who, bo, Wp, bp, (float*)d_out);
}

// Round 13
// 573.631 us; speedup vs baseline: 1.1074x; 1.1074x over previous
//
#include <hip/hip_runtime.h>
#include <hip/hip_bf16.h>

// LSTM B=256 T=512 H=256 E=6 V=10 C=10. fp32 in/out.
// ROUND 13: 128 blocks x 1024 threads (16 waves, 4/SIMD). 2 batch cols/block,
// 8x n-slot dup. Each wave owns 16 rows x 4 gates = 16 MFMAs/step -> smaller
// exposed MFMA tail per wave; 4 waves/SIMD keep matrix pipe fed while others
// run act (r12 lesson: 2 waves/SIMD left ~1000 cyc of scheduling skew).
// INT8 MFMA (mfma_i32_16x16x64_i8), register-resident per-row-quantized
// weights (64 VGPR), h @127 double-buffered LDS, 1 barrier/step.
// acc select: 3 constant-index cndmasks/gate (r9 lesson: never divergent-index
// a register array). Plain predicated byte h-store (r12: conflicts are off the
// critical path; shfl packing only added chain latency). No clamps (|pre|
// bounded ~10 sigma below exp2 overflow). Merged-rcp activations (8 transc).

typedef __attribute__((ext_vector_type(4))) int   int4v;
typedef __attribute__((ext_vector_type(4))) float float4v;

#define MFMA_I8(a, b, c) __builtin_amdgcn_mfma_i32_16x16x64_i8(a, b, c, 0, 0, 0)

#define K_TANH (-2.8853900817779268f)   // exp2(K_TANH*x) = e^(-2x)
#define K_SIG  (-1.4426950408889634f)   // exp2(K_SIG*x)  = e^(-x)

#define HSTRIDE 320                     // bytes per col in hbuf: 80 dw == 16 mod 32

__device__ __forceinline__ short f2b(float f) {
    __hip_bfloat16 b = __float2bfloat16(f); return *(short*)&b;
}
__device__ __forceinline__ float b2f(short s) {
    union { unsigned int u; float f; } v; v.u = ((unsigned int)(unsigned short)s) << 16; return v.f;
}
__device__ __forceinline__ float fexp2(float x) {
#if __has_builtin(__builtin_amdgcn_exp2f)
    return __builtin_amdgcn_exp2f(x);
#else
    return __expf(x * 0.6931471805599453f);
#endif
}
__device__ __forceinline__ float frcp(float x) { return __builtin_amdgcn_rcpf(x); }

__global__ __attribute__((amdgpu_flat_work_group_size(1024, 1024), amdgpu_waves_per_eu(4, 4)))
void lstm_i8(
    const int* __restrict__ x,
    const float* __restrict__ emb,
    const float* __restrict__ Wxg, const float* __restrict__ Whg, const float* __restrict__ bg,
    const float* __restrict__ Wxi, const float* __restrict__ Whi, const float* __restrict__ bi,
    const float* __restrict__ Wxf, const float* __restrict__ Whf, const float* __restrict__ bff,
    const float* __restrict__ Wxo, const float* __restrict__ Who, const float* __restrict__ bo,
    const float* __restrict__ Wp, const float* __restrict__ bp,
    float* __restrict__ out)
{
    const int tid = threadIdx.x, bid = blockIdx.x;
    const int c0 = bid * 2;                 // 2 batch columns per block
    const int w = tid >> 6, lane = tid & 63;
    const int l = lane & 15, q = lane >> 4;
    const int col = l & 1;                  // this thread's column (8x dup)
    const int si  = (l >> 1) & 3;           // acc reg index
    const int dup = (l >> 3) & 1;           // pure duplicate bit
    const int rw  = 16 * w;                 // this wave's 16-row base
    const int row = rw + 4 * q + si;        // this thread's hidden row

    __shared__ __align__(16) unsigned int hbuf[2][2 * HSTRIDE / 4];  // h i8 [parity][col][k]
    __shared__ __align__(16) short hfin[2 * 264];                    // final h bf16 [col][k]
    __shared__ unsigned char xdig2[512 * 2];                         // [t][col]
    __shared__ __align__(16) float tblT[10 * 1024];                  // [d][row][4 gates] f32
    __shared__ float scaleL[4 * 256];                                // per-gate per-row max|W|

    const float* WxT[4] = {Wxg, Wxi, Wxf, Wxo};
    const float* WhT[4] = {Whg, Whi, Whf, Who};

    // ---- init: zero h buf0, stage digits ----
    if (tid < 2 * HSTRIDE / 4) hbuf[0][tid] = 0u;
    if (tid < 1024)
        xdig2[tid] = (unsigned char)x[(c0 + (tid & 1)) * 512 + (tid >> 1)];

    // ---- x-path table, transposed + gate-scale folded: tblT[d][r][g] ----
    for (int i = tid; i < 2560; i += 1024) {
        int d = i >> 8, r = i & 255;          // consecutive lanes -> consecutive r
        float4v v;
        #pragma unroll
        for (int g = 0; g < 4; g++) {
            float s = 0.f;
            #pragma unroll
            for (int e = 0; e < 6; e++) s += WxT[g][r * 6 + e] * emb[d * 6 + e];
            v[g] = s * (g == 0 ? K_TANH : K_SIG);
        }
        *(float4v*)&tblT[d * 1024 + r * 4] = v;
    }

    // ---- weight quantization: per-row scale, i8 A-frags in registers ----
    // A[m=lane&15 -> row rw+l][k = 64kt+16q+j], 16 i8 per lane per kt
    int4v wa[4][4];
    #pragma unroll
    for (int g = 0; g < 4; g++) {
        const float* Wr = WhT[g] + (rw + l) * 256 + q * 16;
        float mx = 0.f;
        #pragma unroll
        for (int kt = 0; kt < 4; kt++)
            #pragma unroll
            for (int c4 = 0; c4 < 4; c4++) {
                float4v v = *(const float4v*)(Wr + kt * 64 + c4 * 4);
                #pragma unroll
                for (int j = 0; j < 4; j++) mx = fmaxf(mx, fabsf(v[j]));
            }
        mx = fmaxf(mx, __shfl_xor(mx, 16));
        mx = fmaxf(mx, __shfl_xor(mx, 32));
        mx = fmaxf(mx, 1e-20f);
        if (q == 0) scaleL[g * 256 + rw + l] = mx;
        float qs = 127.f / mx;
        #pragma unroll
        for (int kt = 0; kt < 4; kt++) {
            int4v f;
            #pragma unroll
            for (int dw = 0; dw < 4; dw++) {
                float4v v = *(const float4v*)(Wr + kt * 64 + dw * 4);
                int word = 0;
                #pragma unroll
                for (int byt = 0; byt < 4; byt++) {
                    int z = (int)rintf(v[byt] * qs);
                    word |= (z & 255) << (8 * byt);
                }
                f[dw] = word;
            }
            wa[g][kt] = f;
        }
    }

    __syncthreads();   // scaleL/tblT/xdig2/hbuf[0] visible

    // ---- loop-invariant: dequant scales (this thread's row), biases (this col) ----
    float dscl[4];
    #pragma unroll
    for (int g = 0; g < 4; g++) {
        float kk = (g == 0 ? K_TANH : K_SIG) * (1.f / 16129.f);   // 127^2
        dscl[g] = scaleL[g * 256 + row] * kk;
    }
    float bSc[4];
    bSc[0] = bg[c0 + col] * K_TANH; bSc[1] = bi[c0 + col] * K_SIG;
    bSc[2] = bff[c0 + col] * K_SIG; bSc[3] = bo[c0 + col] * K_SIG;

    const bool bi1 = (si & 1) != 0;
    const bool bi2 = (si & 2) != 0;
    const float* tprow = tblT + row * 4;     // + d*1024 at runtime
    const int hoff = col * HSTRIDE + row;    // this thread's h byte

    float cs = 0.f, hl = 0.f;

    for (int t = 0; t < 512; t++) {
        const int p = t & 1;
        const char* hbase = (const char*)hbuf[p] + col * HSTRIDE + q * 16;   // dup lanes broadcast

        int4v acc[4];
        #pragma unroll
        for (int g = 0; g < 4; g++) acc[g] = (int4v){0, 0, 0, 0};

        int dg = xdig2[t * 2 + col];
        float4v tb = *(const float4v*)(tprow + dg * 1024);   // {tg,ti,tf,to} kg-scaled

        #pragma unroll
        for (int kt = 0; kt < 4; kt++) {
            int4v hf = *(const int4v*)(hbase + kt * 64);   // B[k=64kt+16q+j][n: col l&1, dup]
            #pragma unroll
            for (int g = 0; g < 4; g++)
                acc[g] = MFMA_I8(wa[g][kt], hf, acc[g]);
        }
        // no barrier: writes go to the other h buffer

        // ---- elementwise: ONE element (row, col) per thread (dup lanes repeat) ----
        // select acc[g][si] via constant-index cndmask tree (3 per gate)
        int av[4];
        #pragma unroll
        for (int g = 0; g < 4; g++) {
            int s0 = bi1 ? acc[g][1] : acc[g][0];
            int s1 = bi1 ? acc[g][3] : acc[g][2];
            av[g]  = bi2 ? s1 : s0;
        }
        {
            float pg = fmaf((float)av[0], dscl[0], tb[0] + bSc[0]);
            float pi = fmaf((float)av[1], dscl[1], tb[1] + bSc[1]);
            float pf = fmaf((float)av[2], dscl[2], tb[2] + bSc[2]);
            float po = fmaf((float)av[3], dscl[3], tb[3] + bSc[3]);
            float Eg = fexp2(pg), Ei = fexp2(pi), Ef = fexp2(pf), Eo = fexp2(po);
            // tanh(g)*sig(i) = (1-Eg) / ((1+Eg)(1+Ei));  c += cs*sig(f)
            float t1 = (1.f - Eg) * frcp((1.f + Eg) * (1.f + Ei));
            float c  = fmaf(cs, frcp(1.f + Ef), t1);
            cs = c;
            float Ec = fexp2(K_TANH * c);
            float hh = (1.f - Ec) * frcp((1.f + Ec) * (1.f + Eo));   // tanh(c)*sig(o)
            hl = hh;
            if (dup == 0)
                *((char*)hbuf[1 - p] + hoff) = (char)((int)rintf(hh * 127.f));
        }
        __syncthreads();   // h_t (other buffer) fully written; h_{t-1} reads all done
    }

    // ---- stage final h (exact f32->bf16) for projection ----
    if (dup == 0) hfin[col * 264 + row] = f2b(hl);
    __syncthreads();

    // ---- projection: out[c0+col][cls] = Wp[cls] . h_final + bp[cls] ----
    if (tid < 20) {
        int pc = tid / 10, cls = tid - pc * 10;
        const short* hcol = &hfin[pc * 264];
        const float* wrow = Wp + cls * 256;
        float s = 0.f;
        #pragma unroll 8
        for (int k = 0; k < 256; k++) s += b2f(hcol[k]) * wrow[k];
        out[(c0 + pc) * 10 + cls] = s + bp[cls];
    }
}

extern "C" void kernel_launch(void* const* d_in, const int* in_sizes, int n_in,
                              void* d_out, int out_size, void* d_ws, size_t ws_size,
                              hipStream_t stream) {
    const int*   x   = (const int*)d_in[0];
    const float* emb = (const float*)d_in[1];
    const float* Wxg = (const float*)d_in[2];
    const float* Whg = (const float*)d_in[3];
    const float* bg  = (const float*)d_in[4];
    const float* Wxi = (const float*)d_in[5];
    const float* Whi = (const float*)d_in[6];
    const float* bi  = (const float*)d_in[7];
    const float* Wxf = (const float*)d_in[8];
    const float* Whf = (const float*)d_in[9];
    const float* bff = (const float*)d_in[10];
    const float* Wxo = (const float*)d_in[11];
    const float* Who = (const float*)d_in[12];
    const float* bo  = (const float*)d_in[13];
    const float* Wp  = (const float*)d_in[14];
    const float* bp  = (const float*)d_in[15];

    hipLaunchKernelGGL(lstm_i8, dim3(128), dim3(1024), 0, stream,
                       x, emb, Wxg, Whg, bg, Wxi, Whi, bi, Wxf, Whf, bff,
                       Wxo, Who, bo, Wp, bp, (float*)d_out);
}

// Round 15
// 555.942 us; speedup vs baseline: 1.1426x; 1.0318x over previous
//
#include <hip/hip_runtime.h>
#include <hip/hip_bf16.h>

// LSTM B=256 T=512 H=256 E=6 V=10 C=10. fp32 in/out.
// ROUND 15: r14 with the tblC init indexing FIXED (per-col table is 2560
// entries = 10 digits x 256 rows; r14 used >>11/&2047 -> digits 8-9 poisoned
// and OOB writes corrupted scaleL -> inf/NaN). Structure: 128 blocks x 1024
// thr (16 waves, 4/SIMD), 2 cols/block, 8x n-dup, 1 elem/thread.
//  - bias folded into per-col x-table tblC[col][d][row][4g] (80 KB LDS)
//  - single-rcp c-update: 5 exp2 + 2 rcp per element
//  - kt-split dual accumulators on g0/g1 (shorter MFMA dep chain)
// INT8 MFMA (mfma_i32_16x16x64_i8), register-resident per-row-quantized
// weights, h @127 double-buffered LDS, 1 barrier/step. acc select = constant-
// index cndmask tree (r9: never divergent-index a register array).

typedef __attribute__((ext_vector_type(4))) int   int4v;
typedef __attribute__((ext_vector_type(4))) float float4v;

#define MFMA_I8(a, b, c) __builtin_amdgcn_mfma_i32_16x16x64_i8(a, b, c, 0, 0, 0)

#define K_TANH (-2.8853900817779268f)   // exp2(K_TANH*x) = e^(-2x)
#define K_SIG  (-1.4426950408889634f)   // exp2(K_SIG*x)  = e^(-x)

#define HSTRIDE 320                     // bytes per col in hbuf: 80 dw == 16 mod 32

__device__ __forceinline__ short f2b(float f) {
    __hip_bfloat16 b = __float2bfloat16(f); return *(short*)&b;
}
__device__ __forceinline__ float b2f(short s) {
    union { unsigned int u; float f; } v; v.u = ((unsigned int)(unsigned short)s) << 16; return v.f;
}
__device__ __forceinline__ float fexp2(float x) {
#if __has_builtin(__builtin_amdgcn_exp2f)
    return __builtin_amdgcn_exp2f(x);
#else
    return __expf(x * 0.6931471805599453f);
#endif
}
__device__ __forceinline__ float frcp(float x) { return __builtin_amdgcn_rcpf(x); }

__global__ __attribute__((amdgpu_flat_work_group_size(1024, 1024), amdgpu_waves_per_eu(4, 4)))
void lstm_i8(
    const int* __restrict__ x,
    const float* __restrict__ emb,
    const float* __restrict__ Wxg, const float* __restrict__ Whg, const float* __restrict__ bg,
    const float* __restrict__ Wxi, const float* __restrict__ Whi, const float* __restrict__ bi,
    const float* __restrict__ Wxf, const float* __restrict__ Whf, const float* __restrict__ bff,
    const float* __restrict__ Wxo, const float* __restrict__ Who, const float* __restrict__ bo,
    const float* __restrict__ Wp, const float* __restrict__ bp,
    float* __restrict__ out)
{
    const int tid = threadIdx.x, bid = blockIdx.x;
    const int c0 = bid * 2;                 // 2 batch columns per block
    const int w = tid >> 6, lane = tid & 63;
    const int l = lane & 15, q = lane >> 4;
    const int col = l & 1;                  // this thread's column (8x dup)
    const int si  = (l >> 1) & 3;           // acc reg index
    const int dup = (l >> 3) & 1;           // pure duplicate bit
    const int rw  = 16 * w;                 // this wave's 16-row base
    const int row = rw + 4 * q + si;        // this thread's hidden row

    __shared__ __align__(16) unsigned int hbuf[2][2 * HSTRIDE / 4];  // h i8 [parity][col][k]
    __shared__ __align__(16) short hfin[2 * 264];                    // final h bf16 [col][k]
    __shared__ unsigned char xdig2[512 * 2];                         // [t][col]
    __shared__ __align__(16) float tblC[2 * 10 * 1024];              // [col][d][row][4g], bias folded
    __shared__ float scaleL[4 * 256];                                // per-gate per-row max|W|

    const float* WxT[4] = {Wxg, Wxi, Wxf, Wxo};
    const float* WhT[4] = {Whg, Whi, Whf, Who};
    const float* bT[4]  = {bg, bi, bff, bo};

    // ---- init: zero h buf0, stage digits ----
    if (tid < 2 * HSTRIDE / 4) hbuf[0][tid] = 0u;
    if (tid < 1024)
        xdig2[tid] = (unsigned char)x[(c0 + (tid & 1)) * 512 + (tid >> 1)];

    // ---- x-path table per col, bias + gate-scale folded: tblC[c][d][r][g] ----
    // 5120 float4 entries = 2 cols x 10 digits x 256 rows (2560 per col!)
    for (int i = tid; i < 5120; i += 1024) {
        int cc  = i / 2560;                   // 0 or 1
        int rem = i - cc * 2560;              // [0,2560)
        int d = rem >> 8, r = rem & 255;      // d in [0,10), consecutive lanes -> consecutive r
        float4v v;
        #pragma unroll
        for (int g = 0; g < 4; g++) {
            float s = 0.f;
            #pragma unroll
            for (int e = 0; e < 6; e++) s += WxT[g][r * 6 + e] * emb[d * 6 + e];
            v[g] = (s + bT[g][c0 + cc]) * (g == 0 ? K_TANH : K_SIG);
        }
        *(float4v*)&tblC[cc * 10240 + d * 1024 + r * 4] = v;
    }

    // ---- weight quantization: per-row scale, i8 A-frags in registers ----
    // A[m=lane&15 -> row rw+l][k = 64kt+16q+j], 16 i8 per lane per kt
    int4v wa[4][4];
    #pragma unroll
    for (int g = 0; g < 4; g++) {
        const float* Wr = WhT[g] + (rw + l) * 256 + q * 16;
        float mx = 0.f;
        #pragma unroll
        for (int kt = 0; kt < 4; kt++)
            #pragma unroll
            for (int c4 = 0; c4 < 4; c4++) {
                float4v v = *(const float4v*)(Wr + kt * 64 + c4 * 4);
                #pragma unroll
                for (int j = 0; j < 4; j++) mx = fmaxf(mx, fabsf(v[j]));
            }
        mx = fmaxf(mx, __shfl_xor(mx, 16));
        mx = fmaxf(mx, __shfl_xor(mx, 32));
        mx = fmaxf(mx, 1e-20f);
        if (q == 0) scaleL[g * 256 + rw + l] = mx;
        float qs = 127.f / mx;
        #pragma unroll
        for (int kt = 0; kt < 4; kt++) {
            int4v f;
            #pragma unroll
            for (int dw = 0; dw < 4; dw++) {
                float4v v = *(const float4v*)(Wr + kt * 64 + dw * 4);
                int word = 0;
                #pragma unroll
                for (int byt = 0; byt < 4; byt++) {
                    int z = (int)rintf(v[byt] * qs);
                    word |= (z & 255) << (8 * byt);
                }
                f[dw] = word;
            }
            wa[g][kt] = f;
        }
    }

    __syncthreads();   // scaleL/tblC/xdig2/hbuf[0] visible

    // ---- loop-invariant: dequant scales (this thread's row) ----
    float dscl[4];
    #pragma unroll
    for (int g = 0; g < 4; g++) {
        float kk = (g == 0 ? K_TANH : K_SIG) * (1.f / 16129.f);   // 127^2
        dscl[g] = scaleL[g * 256 + row] * kk;
    }

    const bool bi1 = (si & 1) != 0;
    const bool bi2 = (si & 2) != 0;
    const float* tprow = tblC + col * 10240 + row * 4;   // + d*1024 at runtime
    const int hoff = col * HSTRIDE + row;                // this thread's h byte

    float cs = 0.f, hl = 0.f;

    for (int t = 0; t < 512; t++) {
        const int p = t & 1;
        const char* hbase = (const char*)hbuf[p] + col * HSTRIDE + q * 16;   // dup lanes broadcast

        int dg = xdig2[t * 2 + col];
        float4v tb = *(const float4v*)(tprow + dg * 1024);   // {tg,ti,tf,to} bias+kg folded

        // g0/g1: kt-split dual accumulators (shorter dep chain); g2/g3: single
        int4v a0e = {0,0,0,0}, a0o = {0,0,0,0};
        int4v a1e = {0,0,0,0}, a1o = {0,0,0,0};
        int4v a2  = {0,0,0,0}, a3  = {0,0,0,0};
        int4v hf0 = *(const int4v*)(hbase + 0 * 64);
        int4v hf1 = *(const int4v*)(hbase + 1 * 64);
        int4v hf2 = *(const int4v*)(hbase + 2 * 64);
        int4v hf3 = *(const int4v*)(hbase + 3 * 64);
        a0e = MFMA_I8(wa[0][0], hf0, a0e); a0o = MFMA_I8(wa[0][1], hf1, a0o);
        a1e = MFMA_I8(wa[1][0], hf0, a1e); a1o = MFMA_I8(wa[1][1], hf1, a1o);
        a2  = MFMA_I8(wa[2][0], hf0, a2);  a2  = MFMA_I8(wa[2][1], hf1, a2);
        a3  = MFMA_I8(wa[3][0], hf0, a3);  a3  = MFMA_I8(wa[3][1], hf1, a3);
        a0e = MFMA_I8(wa[0][2], hf2, a0e); a0o = MFMA_I8(wa[0][3], hf3, a0o);
        a1e = MFMA_I8(wa[1][2], hf2, a1e); a1o = MFMA_I8(wa[1][3], hf3, a1o);
        a2  = MFMA_I8(wa[2][2], hf2, a2);  a2  = MFMA_I8(wa[2][3], hf3, a2);
        a3  = MFMA_I8(wa[3][2], hf2, a3);  a3  = MFMA_I8(wa[3][3], hf3, a3);
        int4v acc0, acc1;
        #pragma unroll
        for (int i = 0; i < 4; i++) { acc0[i] = a0e[i] + a0o[i]; acc1[i] = a1e[i] + a1o[i]; }
        // no barrier: writes go to the other h buffer

        // ---- elementwise: ONE element (row, col) per thread (dup lanes repeat) ----
        // select acc[si] via constant-index cndmask tree (3 per gate)
        int av0, av1, av2, av3;
        { int s0 = bi1 ? acc0[1] : acc0[0]; int s1 = bi1 ? acc0[3] : acc0[2]; av0 = bi2 ? s1 : s0; }
        { int s0 = bi1 ? acc1[1] : acc1[0]; int s1 = bi1 ? acc1[3] : acc1[2]; av1 = bi2 ? s1 : s0; }
        { int s0 = bi1 ? a2[1]   : a2[0];   int s1 = bi1 ? a2[3]   : a2[2];   av2 = bi2 ? s1 : s0; }
        { int s0 = bi1 ? a3[1]   : a3[0];   int s1 = bi1 ? a3[3]   : a3[2];   av3 = bi2 ? s1 : s0; }
        {
            float pg = fmaf((float)av0, dscl[0], tb[0]);
            float pi = fmaf((float)av1, dscl[1], tb[1]);
            float pf = fmaf((float)av2, dscl[2], tb[2]);
            float po = fmaf((float)av3, dscl[3], tb[3]);
            float Eg = fexp2(pg), Ei = fexp2(pi), Ef = fexp2(pf), Eo = fexp2(po);
            // c = [(1-Eg)(1+Ef) + cs(1+Eg)(1+Ei)] / [(1+Eg)(1+Ei)(1+Ef)]  (one rcp)
            float m1  = (1.f + Eg) * (1.f + Ei);
            float fp1 = 1.f + Ef;
            float num = fmaf(cs, m1, (1.f - Eg) * fp1);
            float c   = num * frcp(m1 * fp1);
            cs = c;
            float Ec = fexp2(K_TANH * c);
            float hh = (1.f - Ec) * frcp((1.f + Ec) * (1.f + Eo));   // tanh(c)*sig(o)
            hl = hh;
            if (dup == 0)
                *((char*)hbuf[1 - p] + hoff) = (char)((int)rintf(hh * 127.f));
        }
        __syncthreads();   // h_t (other buffer) fully written; h_{t-1} reads all done
    }

    // ---- stage final h (exact f32->bf16) for projection ----
    if (dup == 0) hfin[col * 264 + row] = f2b(hl);
    __syncthreads();

    // ---- projection: out[c0+col][cls] = Wp[cls] . h_final + bp[cls] ----
    if (tid < 20) {
        int pc = tid / 10, cls = tid - pc * 10;
        const short* hcol = &hfin[pc * 264];
        const float* wrow = Wp + cls * 256;
        float s = 0.f;
        #pragma unroll 8
        for (int k = 0; k < 256; k++) s += b2f(hcol[k]) * wrow[k];
        out[(c0 + pc) * 10 + cls] = s + bp[cls];
    }
}

extern "C" void kernel_launch(void* const* d_in, const int* in_sizes, int n_in,
                              void* d_out, int out_size, void* d_ws, size_t ws_size,
                              hipStream_t stream) {
    const int*   x   = (const int*)d_in[0];
    const float* emb = (const float*)d_in[1];
    const float* Wxg = (const float*)d_in[2];
    const float* Whg = (const float*)d_in[3];
    const float* bg  = (const float*)d_in[4];
    const float* Wxi = (const float*)d_in[5];
    const float* Whi = (const float*)d_in[6];
    const float* bi  = (const float*)d_in[7];
    const float* Wxf = (const float*)d_in[8];
    const float* Whf = (const float*)d_in[9];
    const float* bff = (const float*)d_in[10];
    const float* Wxo = (const float*)d_in[11];
    const float* Who = (const float*)d_in[12];
    const float* bo  = (const float*)d_in[13];
    const float* Wp  = (const float*)d_in[14];
    const float* bp  = (const float*)d_in[15];

    hipLaunchKernelGGL(lstm_i8, dim3(128), dim3(1024), 0, stream,
                       x, emb, Wxg, Whg, bg, Wxi, Whi, bi, Wxf, Whf, bff,
                       Wxo, Who, bo, Wp, bp, (float*)d_out);
}